// Round 3
// baseline (160.253 us; speedup 1.0000x reference)
//
#include <hip/hip_runtime.h>

#define ED 256
#define NHEAD 8
#define NPTS 8
#define DHEAD 32
#define QPB 8   // queries per block: 4 waves x 2 queries (one per 32-lane half)

typedef _Float16 half8v __attribute__((ext_vector_type(8)));

// ---------------------------------------------------------------------------
// Kernel P: fused prep. Blocks [0,bs): per-batch precompute (query broadcast
// -> offsets + softmax weights depend only on batch; ws = off[128],aw[64]).
// Blocks [bs, bs+bs*256): feat fp32 -> fp16, batch-pinned to XCD b so the
// 2MB fp16 map is written into (and stays in) XCD b's L2 for the deform pass.
// R10: NT loads/stores REVERTED (R9 measured +4us regression).
// ---------------------------------------------------------------------------
__global__ __launch_bounds__(256) void prep_kernel(
    const float4* __restrict__ feat, half8v* __restrict__ feat16,
    int per_batch8,
    const float* __restrict__ query,
    const float* __restrict__ W_off, const float* __restrict__ b_off,
    const float* __restrict__ W_attn, const float* __restrict__ b_attn,
    float* __restrict__ ws, int bs)
{
    const int t = threadIdx.x;

    if ((int)blockIdx.x >= bs) {
        // ---------------- convert role ----------------
        const int cid    = blockIdx.x - bs;
        const int b      = cid % bs;
        const int chunk  = cid / bs;
        const int nchunk = (gridDim.x - bs) / bs;
        const size_t base = (size_t)b * per_batch8;
        for (int i = chunk * 256 + t; i < per_batch8; i += nchunk * 256) {
            const size_t idx = base + i;
            const float4 f0 = feat[2 * idx];
            const float4 f1 = feat[2 * idx + 1];
            half8v h;
            h[0] = (_Float16)f0.x; h[1] = (_Float16)f0.y;
            h[2] = (_Float16)f0.z; h[3] = (_Float16)f0.w;
            h[4] = (_Float16)f1.x; h[5] = (_Float16)f1.y;
            h[6] = (_Float16)f1.z; h[7] = (_Float16)f1.w;
            feat16[idx] = h;
        }
        return;
    }

    // ---------------- precompute role ----------------
    const int b = blockIdx.x;
    __shared__ float sq[ED];
    __shared__ float red[256];
    __shared__ float sattn[64];

    sq[t] = query[b * ED + t];
    __syncthreads();

    {
        const int col  = t & 127;
        const int half = t >> 7;
        const float* Wp = W_off + (size_t)half * 128 * 128 + col;
        const float* qp = sq + half * 128;
        float a0 = 0.f, a1 = 0.f, a2 = 0.f, a3 = 0.f;
        #pragma unroll 8
        for (int k = 0; k < 128; k += 4) {
            a0 = fmaf(qp[k + 0], Wp[(k + 0) * 128], a0);
            a1 = fmaf(qp[k + 1], Wp[(k + 1) * 128], a1);
            a2 = fmaf(qp[k + 2], Wp[(k + 2) * 128], a2);
            a3 = fmaf(qp[k + 3], Wp[(k + 3) * 128], a3);
        }
        red[t] = (a0 + a1) + (a2 + a3);
    }
    __syncthreads();
    if (t < 128) ws[b * 192 + t] = fmaxf(red[t] + red[t + 128] + b_off[t], 0.0f);
    __syncthreads();

    {
        const int col = t & 63;
        const int qtr = t >> 6;
        const float* Wp = W_attn + (size_t)qtr * 64 * 64 + col;
        const float* qp = sq + qtr * 64;
        float a0 = 0.f, a1 = 0.f, a2 = 0.f, a3 = 0.f;
        #pragma unroll 8
        for (int k = 0; k < 64; k += 4) {
            a0 = fmaf(qp[k + 0], Wp[(k + 0) * 64], a0);
            a1 = fmaf(qp[k + 1], Wp[(k + 1) * 64], a1);
            a2 = fmaf(qp[k + 2], Wp[(k + 2) * 64], a2);
            a3 = fmaf(qp[k + 3], Wp[(k + 3) * 64], a3);
        }
        red[t] = (a0 + a1) + (a2 + a3);
    }
    __syncthreads();
    if (t < 64) {
        sattn[t] = fmaxf(red[t] + red[t + 64] + red[t + 128] + red[t + 192]
                         + b_attn[t], 0.0f);
    }
    __syncthreads();
    if (t < 64) {
        const int hh = t >> 3;
        float m = -1e30f;
        #pragma unroll
        for (int p = 0; p < NPTS; ++p) m = fmaxf(m, sattn[hh * NPTS + p]);
        float s = 0.0f;
        #pragma unroll
        for (int p = 0; p < NPTS; ++p) s += expf(sattn[hh * NPTS + p] - m);
        ws[b * 192 + 128 + t] = expf(sattn[t] - m) / s;
    }
}

// ---------------------------------------------------------------------------
// Kernel B v10 = v8 structure + FOLDED 4x4-PATCH GATHER.
// Offsets are relu(q.W_off), sigma~0.32px => all 8 points of a (q,h) fall in
// a <=4x4 cell patch anchored at floor(ref*W-0.5) (needs deltamax<2; actual
// max ~1.06 = 3.3 sigma over 1024 samples). Bilinear+point-sum is linear, so
// phase 1 folds 8pts x 4corners into 16 per-cell weights (LDS atomicAdd,
// ds_add_f32); phase 2 gathers only the 16 patch slices:
//   16 loads + 128 FMA / thread (was 32 loads + 256 FMA). Gather traffic
//   512MB -> 256MB. Validity/clamp per corner identical to v8.
//  - wave = 2 queries (one per 32-lane half); thread = 8 fp16 channels.
//  - sched_barrier ISSUE/CONSUME pipeline: rows r0,r1,r2 in flight (12 loads)
//    before first consume.
//  - blockIdx % bs pins batch b to XCD b (matches convert's placement).
// ---------------------------------------------------------------------------
__global__ __launch_bounds__(256, 4) void deform_attn_kernel(
    const _Float16* __restrict__ feat16, // [bs, nq, NHEAD, DHEAD] fp16
    const float* __restrict__ ref2d,     // [bs, nq, 1, 2]
    const float* __restrict__ query,     // [bs, 1, ED]
    const float* __restrict__ ln_g, const float* __restrict__ ln_b,
    const float* __restrict__ ws,        // [bs, 192]
    const int* __restrict__ Hp, const int* __restrict__ Wp,
    float* __restrict__ out,             // [bs, nq, ED]
    int nq, int bs)
{
    const int blk = blockIdx.x;
    const int b = blk % bs;                    // XCD swizzle
    const int qbase = (blk / bs) * QPB;
    const int t = threadIdx.x;

    __shared__ float s_off[128];
    __shared__ float s_aw[64];
    __shared__ float s_ref[QPB * 2];
    __shared__ float s_w16[QPB * NHEAD * 16];  // [q][h][cell]: folded weights

    // zero the weight accumulator (atomicAdd target)
    #pragma unroll
    for (int i = t; i < QPB * NHEAD * 16; i += 256) s_w16[i] = 0.0f;

    if (t < 128)      s_off[t] = ws[b * 192 + t];
    else if (t < 192) s_aw[t - 128] = ws[b * 192 + t];
    else if (t < 192 + QPB * 2) {
        const int i = t - 192;                 // i = qL*2 + j
        s_ref[i] = ref2d[(b * nq + qbase + (i >> 1)) * 2 + (i & 1)];
    }
    const int H = Hp[0];
    const int W = Wp[0];
    __syncthreads();

    // ---- Phase 1: fold 8*64 (q,h,p) corner weights into [q][h][4x4] ----
    #pragma unroll
    for (int k = 0; k < 2; ++k) {
        const int u  = t + k * 256;            // 512 tasks
        const int qL = u >> 6;
        const int l  = u & 63;
        const int p  = l >> 3;
        const int h  = l & 7;
        const int hp = h * 8 + p;

        const float xb = s_ref[qL * 2 + 0] * (float)W - 0.5f;
        const float yb = s_ref[qL * 2 + 1] * (float)H - 0.5f;
        const float x = xb + s_off[hp * 2 + 0];
        const float y = yb + s_off[hp * 2 + 1];
        const float aw = s_aw[hp];

        const float xf = floorf(x);
        const float yf = floorf(y);
        const int ix = (int)xf;
        const int iy = (int)yf;
        const float wx = x - xf;
        const float wy = y - yf;
        const int X = (int)floorf(xb);         // patch anchor (offsets >= 0)
        const int Y = (int)floorf(yb);
        const int dx = ix - X;                 // 0..2 (delta < 2)
        const int dy = iy - Y;

        const bool vx0 = (ix >= 0) && (ix < W);
        const bool vx1 = (ix + 1 >= 0) && (ix + 1 < W);
        const bool vy0 = (iy >= 0) && (iy < H);
        const bool vy1 = (iy + 1 >= 0) && (iy + 1 < H);

        const float awx = aw * wx, awix = aw - awx;     // aw*(1-wx)
        const float w00 = (vx0 && vy0) ? awix * (1.0f - wy) : 0.0f;
        const float w01 = (vx1 && vy0) ? awx  * (1.0f - wy) : 0.0f;
        const float w10 = (vx0 && vy1) ? awix * wy          : 0.0f;
        const float w11 = (vx1 && vy1) ? awx  * wy          : 0.0f;

        if (dx >= 0 && dx <= 2 && dy >= 0 && dy <= 2) {  // always true for d<2
            float* wp = &s_w16[(qL * 8 + h) * 16 + dy * 4 + dx];
            atomicAdd(wp + 0, w00);
            atomicAdd(wp + 1, w01);
            atomicAdd(wp + 4, w10);
            atomicAdd(wp + 5, w11);
        }
    }
    __syncthreads();

    // ---- Phase 2: pipelined 4x4-patch gather. wave = 2 queries ----
    const int wave = t >> 6;
    const int lane = t & 63;
    const int half = lane >> 5;
    const int l32  = lane & 31;
    const int h    = l32 >> 2;                 // head
    const int c16  = l32 & 3;                  // 16B chunk within 64B slice
    const int qloc = wave * 2 + half;
    const int q    = qbase + qloc;

    const char* fb = (const char*)feat16 + (size_t)b * nq * (NHEAD * DHEAD * 2);
    const unsigned laneofs = (unsigned)(h * 64 + c16 * 16);

    // epilogue operands issued early (independent of gather)
    const float4 qv0 = *(const float4*)(query + b * ED + l32 * 8);
    const float4 qv1 = *(const float4*)(query + b * ED + l32 * 8 + 4);
    const float4 g0  = *(const float4*)(ln_g + l32 * 8);
    const float4 g1  = *(const float4*)(ln_g + l32 * 8 + 4);
    const float4 be0 = *(const float4*)(ln_b + l32 * 8);
    const float4 be1 = *(const float4*)(ln_b + l32 * 8 + 4);

    // folded weights (rows of the 4x4 patch)
    const int g16 = (qloc * 8 + h) * 16;
    const float4 w0 = *(const float4*)&s_w16[g16 + 0];
    const float4 w1 = *(const float4*)&s_w16[g16 + 4];
    const float4 w2 = *(const float4*)&s_w16[g16 + 8];
    const float4 w3 = *(const float4*)&s_w16[g16 + 12];

    // patch cell addresses: clamped rows/cols (weights are 0 for OOB corners)
    const float xb = s_ref[qloc * 2 + 0] * (float)W - 0.5f;
    const float yb = s_ref[qloc * 2 + 1] * (float)H - 0.5f;
    const int X = (int)floorf(xb);
    const int Y = (int)floorf(yb);
    const unsigned c0 = (unsigned)min(max(X + 0, 0), W - 1) << 9;
    const unsigned c1 = (unsigned)min(max(X + 1, 0), W - 1) << 9;
    const unsigned c2 = (unsigned)min(max(X + 2, 0), W - 1) << 9;
    const unsigned c3 = (unsigned)min(max(X + 3, 0), W - 1) << 9;
    const unsigned r0 = (unsigned)(min(max(Y + 0, 0), H - 1) * W) << 9;
    const unsigned r1 = (unsigned)(min(max(Y + 1, 0), H - 1) * W) << 9;
    const unsigned r2 = (unsigned)(min(max(Y + 2, 0), H - 1) * W) << 9;
    const unsigned r3 = (unsigned)(min(max(Y + 3, 0), H - 1) * W) << 9;

    float acc[8] = {0.f, 0.f, 0.f, 0.f, 0.f, 0.f, 0.f, 0.f};

#define ISSUE(R, rofs) \
    const half8v R##0 = *(const half8v*)(fb + (rofs + c0 + laneofs)); \
    const half8v R##1 = *(const half8v*)(fb + (rofs + c1 + laneofs)); \
    const half8v R##2 = *(const half8v*)(fb + (rofs + c2 + laneofs)); \
    const half8v R##3 = *(const half8v*)(fb + (rofs + c3 + laneofs));

#define CONSUME(R, wv) \
    _Pragma("unroll") \
    for (int j = 0; j < 8; ++j) { \
        acc[j] = fmaf(wv.x, (float)R##0[j], acc[j]); \
        acc[j] = fmaf(wv.y, (float)R##1[j], acc[j]); \
        acc[j] = fmaf(wv.z, (float)R##2[j], acc[j]); \
        acc[j] = fmaf(wv.w, (float)R##3[j], acc[j]); \
    }

    ISSUE(d0, r0)
    ISSUE(d1, r1)
    ISSUE(d2, r2)
    __builtin_amdgcn_sched_barrier(0);
    CONSUME(d0, w0)
    ISSUE(d3, r3)
    __builtin_amdgcn_sched_barrier(0);
    CONSUME(d1, w1)
    __builtin_amdgcn_sched_barrier(0);
    CONSUME(d2, w2)
    CONSUME(d3, w3)

#undef ISSUE
#undef CONSUME

    // ---- Phase 3: residual + half-wave (32-lane) LayerNorm ----
    float r[8];
    r[0] = acc[0] + qv0.x; r[1] = acc[1] + qv0.y;
    r[2] = acc[2] + qv0.z; r[3] = acc[3] + qv0.w;
    r[4] = acc[4] + qv1.x; r[5] = acc[5] + qv1.y;
    r[6] = acc[6] + qv1.z; r[7] = acc[7] + qv1.w;

    float s = 0.f, ss = 0.f;
    #pragma unroll
    for (int j = 0; j < 8; ++j) {
        s += r[j];
        ss = fmaf(r[j], r[j], ss);
    }
    #pragma unroll
    for (int m = 1; m < 32; m <<= 1) {         // stays within 32-lane half
        s  += __shfl_xor(s, m, 64);
        ss += __shfl_xor(ss, m, 64);
    }
    const float mean = s * (1.0f / ED);
    const float var  = ss * (1.0f / ED) - mean * mean;
    const float inv  = rsqrtf(var + 1e-5f);

    float4 o0, o1;
    o0.x = (r[0] - mean) * inv * g0.x + be0.x;
    o0.y = (r[1] - mean) * inv * g0.y + be0.y;
    o0.z = (r[2] - mean) * inv * g0.z + be0.z;
    o0.w = (r[3] - mean) * inv * g0.w + be0.w;
    o1.x = (r[4] - mean) * inv * g1.x + be1.x;
    o1.y = (r[5] - mean) * inv * g1.y + be1.y;
    o1.z = (r[6] - mean) * inv * g1.z + be1.z;
    o1.w = (r[7] - mean) * inv * g1.w + be1.w;

    float* op = out + ((size_t)b * nq + q) * ED + l32 * 8;
    *(float4*)op       = o0;
    *(float4*)(op + 4) = o1;
}

extern "C" void kernel_launch(void* const* d_in, const int* in_sizes, int n_in,
                              void* d_out, int out_size, void* d_ws, size_t ws_size,
                              hipStream_t stream)
{
    const float* query  = (const float*)d_in[0];
    const float* feat   = (const float*)d_in[1];
    const float* ref2d  = (const float*)d_in[2];
    const float* W_off  = (const float*)d_in[3];
    const float* b_off  = (const float*)d_in[4];
    const float* W_attn = (const float*)d_in[5];
    const float* b_attn = (const float*)d_in[6];
    const float* ln_g   = (const float*)d_in[7];
    const float* ln_b   = (const float*)d_in[8];
    const int*   Hp     = (const int*)d_in[9];
    const int*   Wp     = (const int*)d_in[10];
    float* out = (float*)d_out;
    float* ws  = (float*)d_ws;

    const int bs = in_sizes[0] / ED;            // 8
    const int nq = in_sizes[2] / (bs * 2);      // h*w = 4096
    const int nfeat = in_sizes[1];              // bs*nq*ED
    const int per_batch8 = nfeat / (bs * 8);    // half8v units per batch

    // ws layout: [0, 1536) floats = precompute; fp16 feat at byte 8192.
    _Float16* feat16 = (_Float16*)((char*)d_ws + 8192);

    prep_kernel<<<bs + bs * 256, 256, 0, stream>>>(
        (const float4*)feat, (half8v*)feat16, per_batch8,
        query, W_off, b_off, W_attn, b_attn, ws, bs);
    deform_attn_kernel<<<bs * nq / QPB, 256, 0, stream>>>((const _Float16*)feat16,
                                                          ref2d, query, ln_g, ln_b,
                                                          ws, Hp, Wp, out, nq, bs);
}

// Round 4
// 134.306 us; speedup vs baseline: 1.1932x; 1.1932x over previous
//
#include <hip/hip_runtime.h>

#define ED 256
#define NHEAD 8
#define NPTS 8
#define DHEAD 32
#define QPB 8   // queries per block: 4 waves x 2 queries (one per 32-lane half)

typedef _Float16 half8v __attribute__((ext_vector_type(8)));

// ---------------------------------------------------------------------------
// Kernel P: fused prep. Blocks [0,bs): per-batch precompute (query broadcast
// -> offsets + softmax weights depend only on batch; ws = off[128],aw[64]).
// Blocks [bs, bs+bs*256): feat fp32 -> fp16, batch-pinned to XCD b so the
// 2MB fp16 map is written into (and stays in) XCD b's L2 for the deform pass.
// R11 = exact revert to the 132.9us R0 baseline (v8). R9 NT: +4us regression.
// R10 folded 4x4 gather: +27us regression (more distinct lines + LDS atomics
// + halved latency-hiding FMA). Both reverted.
// ---------------------------------------------------------------------------
__global__ __launch_bounds__(256) void prep_kernel(
    const float4* __restrict__ feat, half8v* __restrict__ feat16,
    int per_batch8,
    const float* __restrict__ query,
    const float* __restrict__ W_off, const float* __restrict__ b_off,
    const float* __restrict__ W_attn, const float* __restrict__ b_attn,
    float* __restrict__ ws, int bs)
{
    const int t = threadIdx.x;

    if ((int)blockIdx.x >= bs) {
        // ---------------- convert role ----------------
        const int cid    = blockIdx.x - bs;
        const int b      = cid % bs;
        const int chunk  = cid / bs;
        const int nchunk = (gridDim.x - bs) / bs;
        const size_t base = (size_t)b * per_batch8;
        for (int i = chunk * 256 + t; i < per_batch8; i += nchunk * 256) {
            const size_t idx = base + i;
            const float4 f0 = feat[2 * idx];
            const float4 f1 = feat[2 * idx + 1];
            half8v h;
            h[0] = (_Float16)f0.x; h[1] = (_Float16)f0.y;
            h[2] = (_Float16)f0.z; h[3] = (_Float16)f0.w;
            h[4] = (_Float16)f1.x; h[5] = (_Float16)f1.y;
            h[6] = (_Float16)f1.z; h[7] = (_Float16)f1.w;
            feat16[idx] = h;
        }
        return;
    }

    // ---------------- precompute role ----------------
    const int b = blockIdx.x;
    __shared__ float sq[ED];
    __shared__ float red[256];
    __shared__ float sattn[64];

    sq[t] = query[b * ED + t];
    __syncthreads();

    {
        const int col  = t & 127;
        const int half = t >> 7;
        const float* Wp = W_off + (size_t)half * 128 * 128 + col;
        const float* qp = sq + half * 128;
        float a0 = 0.f, a1 = 0.f, a2 = 0.f, a3 = 0.f;
        #pragma unroll 8
        for (int k = 0; k < 128; k += 4) {
            a0 = fmaf(qp[k + 0], Wp[(k + 0) * 128], a0);
            a1 = fmaf(qp[k + 1], Wp[(k + 1) * 128], a1);
            a2 = fmaf(qp[k + 2], Wp[(k + 2) * 128], a2);
            a3 = fmaf(qp[k + 3], Wp[(k + 3) * 128], a3);
        }
        red[t] = (a0 + a1) + (a2 + a3);
    }
    __syncthreads();
    if (t < 128) ws[b * 192 + t] = fmaxf(red[t] + red[t + 128] + b_off[t], 0.0f);
    __syncthreads();

    {
        const int col = t & 63;
        const int qtr = t >> 6;
        const float* Wp = W_attn + (size_t)qtr * 64 * 64 + col;
        const float* qp = sq + qtr * 64;
        float a0 = 0.f, a1 = 0.f, a2 = 0.f, a3 = 0.f;
        #pragma unroll 8
        for (int k = 0; k < 64; k += 4) {
            a0 = fmaf(qp[k + 0], Wp[(k + 0) * 64], a0);
            a1 = fmaf(qp[k + 1], Wp[(k + 1) * 64], a1);
            a2 = fmaf(qp[k + 2], Wp[(k + 2) * 64], a2);
            a3 = fmaf(qp[k + 3], Wp[(k + 3) * 64], a3);
        }
        red[t] = (a0 + a1) + (a2 + a3);
    }
    __syncthreads();
    if (t < 64) {
        sattn[t] = fmaxf(red[t] + red[t + 64] + red[t + 128] + red[t + 192]
                         + b_attn[t], 0.0f);
    }
    __syncthreads();
    if (t < 64) {
        const int hh = t >> 3;
        float m = -1e30f;
        #pragma unroll
        for (int p = 0; p < NPTS; ++p) m = fmaxf(m, sattn[hh * NPTS + p]);
        float s = 0.0f;
        #pragma unroll
        for (int p = 0; p < NPTS; ++p) s += expf(sattn[hh * NPTS + p] - m);
        ws[b * 192 + 128 + t] = expf(sattn[t] - m) / s;
    }
}

// ---------------------------------------------------------------------------
// Kernel B v8 (reverted): forced 2-deep load pipeline.
// Compiler always minimizes VGPR (36) and keeps only one load-batch in
// flight (measured: 0.45 lines/cy/CU, ~2x above latency floor across
// R4-R7; launch_bounds alone never changed VGPR). sched_barrier(0) fences
// pin: [issue pp0, pp2][fence][consume pp0, issue pp4][fence][consume pp2,
// issue pp6][fence][consume pp4, pp6] -> 16 loads in flight per wave.
//  - wave = 2 queries (one per 32-lane half); thread = 8 fp16 channels.
//  - LayerNorm reduce over 32 lanes (shfl_xor m<=16 stays in-half).
//  - blockIdx % bs pins batch b to XCD b (matches convert's placement).
// ---------------------------------------------------------------------------
__global__ __launch_bounds__(256, 4) void deform_attn_kernel(
    const _Float16* __restrict__ feat16, // [bs, nq, NHEAD, DHEAD] fp16
    const float* __restrict__ ref2d,     // [bs, nq, 1, 2]
    const float* __restrict__ query,     // [bs, 1, ED]
    const float* __restrict__ ln_g, const float* __restrict__ ln_b,
    const float* __restrict__ ws,        // [bs, 192]
    const int* __restrict__ Hp, const int* __restrict__ Wp,
    float* __restrict__ out,             // [bs, nq, ED]
    int nq, int bs)
{
    const int blk = blockIdx.x;
    const int b = blk % bs;                    // XCD swizzle
    const int qbase = (blk / bs) * QPB;
    const int t = threadIdx.x;

    __shared__ float s_off[128];
    __shared__ float s_aw[64];
    __shared__ float s_ref[QPB * 2];
    __shared__ uint4  s_ofs[QPB * 64];         // [q][p*8+h]: byte offsets
    __shared__ float4 s_wt [QPB * 64];         // [q][p*8+h]: folded weights

    if (t < 128)      s_off[t] = ws[b * 192 + t];
    else if (t < 192) s_aw[t - 128] = ws[b * 192 + t];
    else if (t < 192 + QPB * 2) {
        const int i = t - 192;                 // i = qL*2 + j
        s_ref[i] = ref2d[(b * nq + qbase + (i >> 1)) * 2 + (i & 1)];
    }
    const int H = Hp[0];
    const int W = Wp[0];
    __syncthreads();

    // ---- Phase 1: 8*64 tuples, 2 per thread; entry l -> (p=l>>3, h=l&7) ----
    #pragma unroll
    for (int u = t; u < QPB * 64; u += 256) {
        const int qL = u >> 6;
        const int l  = u & 63;
        const int p  = l >> 3;
        const int h  = l & 7;
        const int hp = h * 8 + p;

        const float x = s_ref[qL * 2 + 0] * (float)W - 0.5f + s_off[hp * 2 + 0];
        const float y = s_ref[qL * 2 + 1] * (float)H - 0.5f + s_off[hp * 2 + 1];
        const float aw = s_aw[hp];

        const float xf = floorf(x);
        const float yf = floorf(y);
        const int ix = (int)xf;
        const int iy = (int)yf;
        const float wx = x - xf;
        const float wy = y - yf;

        const bool vx0 = (ix >= 0) && (ix < W);
        const bool vx1 = (ix + 1 >= 0) && (ix + 1 < W);
        const bool vy0 = (iy >= 0) && (iy < H);
        const bool vy1 = (iy + 1 >= 0) && (iy + 1 < H);
        const int cx0 = min(max(ix, 0), W - 1);
        const int cx1 = min(max(ix + 1, 0), W - 1);
        const int cy0 = min(max(iy, 0), H - 1);
        const int cy1 = min(max(iy + 1, 0), H - 1);

        const int r0 = cy0 * W;
        const int r1 = cy1 * W;
        uint4 ofs;                              // byte offsets, pos stride 512B
        ofs.x = (unsigned)(r0 + cx0) << 9;
        ofs.y = (unsigned)(r0 + cx1) << 9;
        ofs.z = (unsigned)(r1 + cx0) << 9;
        ofs.w = (unsigned)(r1 + cx1) << 9;

        const float awx = aw * wx, awix = aw - awx;     // aw*(1-wx)
        float4 wt;
        wt.x = (vx0 && vy0) ? awix * (1.0f - wy) : 0.0f;
        wt.y = (vx1 && vy0) ? awx  * (1.0f - wy) : 0.0f;
        wt.z = (vx0 && vy1) ? awix * wy          : 0.0f;
        wt.w = (vx1 && vy1) ? awx  * wy          : 0.0f;

        s_ofs[u] = ofs;
        s_wt[u]  = wt;
    }
    __syncthreads();

    // ---- Phase 2: forced-pipeline gather. wave = 2 queries ----
    const int wave = t >> 6;
    const int lane = t & 63;
    const int half = lane >> 5;
    const int l32  = lane & 31;
    const int h    = l32 >> 2;                 // head
    const int c16  = l32 & 3;                  // 16B chunk within 64B slice
    const int qloc = wave * 2 + half;
    const int q    = qbase + qloc;
    const int cb   = qloc * 64 + h;            // + p*8 per point

    const char* fb = (const char*)feat16 + (size_t)b * nq * (NHEAD * DHEAD * 2);
    const unsigned laneofs = (unsigned)(h * 64 + c16 * 16);

    // epilogue operands issued early (independent of gather)
    const float4 qv0 = *(const float4*)(query + b * ED + l32 * 8);
    const float4 qv1 = *(const float4*)(query + b * ED + l32 * 8 + 4);
    const float4 g0  = *(const float4*)(ln_g + l32 * 8);
    const float4 g1  = *(const float4*)(ln_g + l32 * 8 + 4);
    const float4 be0 = *(const float4*)(ln_b + l32 * 8);
    const float4 be1 = *(const float4*)(ln_b + l32 * 8 + 4);

    float acc[8] = {0.f, 0.f, 0.f, 0.f, 0.f, 0.f, 0.f, 0.f};

#define ISSUE(P, pp) \
    const uint4  iA##P = s_ofs[cb + (pp) * 8]; \
    const float4 wA##P = s_wt [cb + (pp) * 8]; \
    const uint4  iB##P = s_ofs[cb + (pp) * 8 + 8]; \
    const float4 wB##P = s_wt [cb + (pp) * 8 + 8]; \
    const half8v A0##P = *(const half8v*)(fb + (iA##P.x + laneofs)); \
    const half8v A1##P = *(const half8v*)(fb + (iA##P.y + laneofs)); \
    const half8v A2##P = *(const half8v*)(fb + (iA##P.z + laneofs)); \
    const half8v A3##P = *(const half8v*)(fb + (iA##P.w + laneofs)); \
    const half8v B0##P = *(const half8v*)(fb + (iB##P.x + laneofs)); \
    const half8v B1##P = *(const half8v*)(fb + (iB##P.y + laneofs)); \
    const half8v B2##P = *(const half8v*)(fb + (iB##P.z + laneofs)); \
    const half8v B3##P = *(const half8v*)(fb + (iB##P.w + laneofs));

#define CONSUME(P) \
    _Pragma("unroll") \
    for (int j = 0; j < 8; ++j) { \
        acc[j] = fmaf(wA##P.x, (float)A0##P[j], acc[j]); \
        acc[j] = fmaf(wA##P.y, (float)A1##P[j], acc[j]); \
        acc[j] = fmaf(wA##P.z, (float)A2##P[j], acc[j]); \
        acc[j] = fmaf(wA##P.w, (float)A3##P[j], acc[j]); \
        acc[j] = fmaf(wB##P.x, (float)B0##P[j], acc[j]); \
        acc[j] = fmaf(wB##P.y, (float)B1##P[j], acc[j]); \
        acc[j] = fmaf(wB##P.z, (float)B2##P[j], acc[j]); \
        acc[j] = fmaf(wB##P.w, (float)B3##P[j], acc[j]); \
    }

    ISSUE(0, 0)
    ISSUE(1, 2)
    __builtin_amdgcn_sched_barrier(0);
    CONSUME(0)
    ISSUE(2, 4)
    __builtin_amdgcn_sched_barrier(0);
    CONSUME(1)
    ISSUE(3, 6)
    __builtin_amdgcn_sched_barrier(0);
    CONSUME(2)
    CONSUME(3)

#undef ISSUE
#undef CONSUME

    // ---- Phase 3: residual + half-wave (32-lane) LayerNorm ----
    float r[8];
    r[0] = acc[0] + qv0.x; r[1] = acc[1] + qv0.y;
    r[2] = acc[2] + qv0.z; r[3] = acc[3] + qv0.w;
    r[4] = acc[4] + qv1.x; r[5] = acc[5] + qv1.y;
    r[6] = acc[6] + qv1.z; r[7] = acc[7] + qv1.w;

    float s = 0.f, ss = 0.f;
    #pragma unroll
    for (int j = 0; j < 8; ++j) {
        s += r[j];
        ss = fmaf(r[j], r[j], ss);
    }
    #pragma unroll
    for (int m = 1; m < 32; m <<= 1) {         // stays within 32-lane half
        s  += __shfl_xor(s, m, 64);
        ss += __shfl_xor(ss, m, 64);
    }
    const float mean = s * (1.0f / ED);
    const float var  = ss * (1.0f / ED) - mean * mean;
    const float inv  = rsqrtf(var + 1e-5f);

    float4 o0, o1;
    o0.x = (r[0] - mean) * inv * g0.x + be0.x;
    o0.y = (r[1] - mean) * inv * g0.y + be0.y;
    o0.z = (r[2] - mean) * inv * g0.z + be0.z;
    o0.w = (r[3] - mean) * inv * g0.w + be0.w;
    o1.x = (r[4] - mean) * inv * g1.x + be1.x;
    o1.y = (r[5] - mean) * inv * g1.y + be1.y;
    o1.z = (r[6] - mean) * inv * g1.z + be1.z;
    o1.w = (r[7] - mean) * inv * g1.w + be1.w;

    float* op = out + ((size_t)b * nq + q) * ED + l32 * 8;
    *(float4*)op       = o0;
    *(float4*)(op + 4) = o1;
}

extern "C" void kernel_launch(void* const* d_in, const int* in_sizes, int n_in,
                              void* d_out, int out_size, void* d_ws, size_t ws_size,
                              hipStream_t stream)
{
    const float* query  = (const float*)d_in[0];
    const float* feat   = (const float*)d_in[1];
    const float* ref2d  = (const float*)d_in[2];
    const float* W_off  = (const float*)d_in[3];
    const float* b_off  = (const float*)d_in[4];
    const float* W_attn = (const float*)d_in[5];
    const float* b_attn = (const float*)d_in[6];
    const float* ln_g   = (const float*)d_in[7];
    const float* ln_b   = (const float*)d_in[8];
    const int*   Hp     = (const int*)d_in[9];
    const int*   Wp     = (const int*)d_in[10];
    float* out = (float*)d_out;
    float* ws  = (float*)d_ws;

    const int bs = in_sizes[0] / ED;            // 8
    const int nq = in_sizes[2] / (bs * 2);      // h*w = 4096
    const int nfeat = in_sizes[1];              // bs*nq*ED
    const int per_batch8 = nfeat / (bs * 8);    // half8v units per batch

    // ws layout: [0, 1536) floats = precompute; fp16 feat at byte 8192.
    _Float16* feat16 = (_Float16*)((char*)d_ws + 8192);

    prep_kernel<<<bs + bs * 256, 256, 0, stream>>>(
        (const float4*)feat, (half8v*)feat16, per_batch8,
        query, W_off, b_off, W_attn, b_attn, ws, bs);
    deform_attn_kernel<<<bs * nq / QPB, 256, 0, stream>>>((const _Float16*)feat16,
                                                          ref2d, query, ln_g, ln_b,
                                                          ws, Hp, Wp, out, nq, bs);
}